// Round 2
// baseline (512.601 us; speedup 1.0000x reference)
//
#include <hip/hip_runtime.h>

// QSScan: quantized selective scan (Mamba-style), int8-in-int32 operands + scalar scales.
// y[b,d,l] = (scan(...) + D*u) * z * sigmoid(z), all fp32.
//
// Parallelization: 16 lanes per (b,d) scan — one lane per state n.
// Chunked over 16 timesteps: each lane precomputes softplus/gate for its own t,
// exchanges (delta, delta*u*B_s) via a per-group LDS row, then all 16 lanes
// advance the recurrence jointly and butterfly-reduce the C-dot each step.

#define LOG2E 1.44269504088896340736f
#define LN2F  0.69314718055994530942f

constexpr int BATCH = 2;
constexpr int DIM   = 4096;
constexpr int LSEQ  = 2048;
constexpr int NST   = 16;

__global__ __launch_bounds__(256, 2) void qsscan_kernel(
    const int* __restrict__ u,  const int* __restrict__ dt,
    const int* __restrict__ Bm, const int* __restrict__ Cm,
    const int* __restrict__ z,  const int* __restrict__ A_log,
    const int* __restrict__ Dv, const int* __restrict__ dt_bias,
    const float* __restrict__ u_sp,  const float* __restrict__ dt_sp,
    const float* __restrict__ A_sp,  const float* __restrict__ B_sp,
    const float* __restrict__ C_sp,  const float* __restrict__ z_sp,
    const float* __restrict__ D_sp,  const float* __restrict__ dtb_sp,
    float* __restrict__ out)
{
    const int tid  = threadIdx.x;
    const int n    = tid & 15;          // state index within scan
    const int grp  = tid >> 4;          // scan-group within block (0..15)
    const int scan = blockIdx.x * 16 + grp;   // 0..8191
    const int b    = scan >> 12;        // scan / DIM
    const int d    = scan & (DIM - 1);

    const float u_s  = *u_sp,  dt_s  = *dt_sp, A_s = *A_sp, B_s = *B_sp;
    const float C_s  = *C_sp,  z_s   = *z_sp,  D_s = *D_sp, dtb_s = *dtb_sp;

    // A2 = A * log2(e), with A = -exp(A_log * A_s); dA = exp2(delta * A2)
    const float A2  = -__builtin_amdgcn_exp2f((float)A_log[d * NST + n] * (A_s * LOG2E)) * LOG2E;
    const float dtb = (float)dt_bias[d] * dtb_s;
    const float Dd  = (float)Dv[d] * D_s;

    const int* up  = u  + (size_t)scan * LSEQ;
    const int* dtp = dt + (size_t)scan * LSEQ;
    const int* zp  = z  + (size_t)scan * LSEQ;
    float*     op  = out + (size_t)scan * LSEQ;
    const int* Bp  = Bm + (size_t)(b * NST + n) * LSEQ;
    const int* Cp  = Cm + (size_t)(b * NST + n) * LSEQ;

    // [grp][j] -> (delta_j, delta_j*u_j*B_s). Pad row to 17 so the 4 groups of a
    // wave hit distinct banks on the broadcast ds_read_b64 (stride 34 banks ≡ +2).
    __shared__ float2 lds[16][17];

    float x = 0.f;

    for (int t0 = 0; t0 < LSEQ; t0 += 16) {
        const int t = t0 + n;   // this lane's own timestep within the chunk

        // ---- per-lane precompute for own timestep (coalesced dword loads)
        const float uf    = (float)up[t]  * u_s;
        const float sdt   = (float)dtp[t] * dt_s + dtb;
        const float e     = __builtin_amdgcn_exp2f(sdt * LOG2E);
        const float delta = __builtin_amdgcn_logf(1.f + e) * LN2F;   // softplus
        const float duB   = delta * uf * B_s;
        const float zf    = (float)zp[t] * z_s;
        const float gate  = zf * __builtin_amdgcn_rcpf(1.f + __builtin_amdgcn_exp2f(-zf * LOG2E));
        const float Du    = Dd * uf;

        // ---- B/C chunk: state n, 16 timesteps (16B vector loads, L2-resident)
        const int4 b0 = *(const int4*)(Bp + t0);
        const int4 b1 = *(const int4*)(Bp + t0 + 4);
        const int4 b2 = *(const int4*)(Bp + t0 + 8);
        const int4 b3 = *(const int4*)(Bp + t0 + 12);
        const int4 c0 = *(const int4*)(Cp + t0);
        const int4 c1 = *(const int4*)(Cp + t0 + 4);
        const int4 c2 = *(const int4*)(Cp + t0 + 8);
        const int4 c3 = *(const int4*)(Cp + t0 + 12);
        const float Bf[16] = {
            (float)b0.x, (float)b0.y, (float)b0.z, (float)b0.w,
            (float)b1.x, (float)b1.y, (float)b1.z, (float)b1.w,
            (float)b2.x, (float)b2.y, (float)b2.z, (float)b2.w,
            (float)b3.x, (float)b3.y, (float)b3.z, (float)b3.w };
        const float Cf[16] = {
            (float)c0.x, (float)c0.y, (float)c0.z, (float)c0.w,
            (float)c1.x, (float)c1.y, (float)c1.z, (float)c1.w,
            (float)c2.x, (float)c2.y, (float)c2.z, (float)c2.w,
            (float)c3.x, (float)c3.y, (float)c3.z, (float)c3.w };

        lds[grp][n] = make_float2(delta, duB);
        __syncthreads();

        float yout = 0.f;
#pragma unroll
        for (int j = 0; j < 16; ++j) {
            const float2 dd = lds[grp][j];           // broadcast read (conflict-free)
            const float dA = __builtin_amdgcn_exp2f(dd.x * A2);
            x = __builtin_fmaf(dA, x, dd.y * Bf[j]);
            float yp = x * Cf[j];
            yp += __shfl_xor(yp, 1);                 // butterfly within 16-lane group
            yp += __shfl_xor(yp, 2);
            yp += __shfl_xor(yp, 4);
            yp += __shfl_xor(yp, 8);
            if (n == j) yout = yp;                   // lane j keeps y_{t0+j}
        }

        // finalize own timestep: y*C_s + D*u, then silu(z) gate; coalesced store
        op[t] = __builtin_fmaf(yout, C_s, Du) * gate;
        __syncthreads();
    }
}

extern "C" void kernel_launch(void* const* d_in, const int* in_sizes, int n_in,
                              void* d_out, int out_size, void* d_ws, size_t ws_size,
                              hipStream_t stream) {
    const int scans = BATCH * DIM;          // 8192
    dim3 grid(scans / 16);                  // 512 blocks, 16 scans per block
    dim3 block(256);
    qsscan_kernel<<<grid, block, 0, stream>>>(
        (const int*)d_in[0], (const int*)d_in[1], (const int*)d_in[2],
        (const int*)d_in[3], (const int*)d_in[4], (const int*)d_in[5],
        (const int*)d_in[6], (const int*)d_in[7],
        (const float*)d_in[8],  (const float*)d_in[9],  (const float*)d_in[10],
        (const float*)d_in[11], (const float*)d_in[12], (const float*)d_in[13],
        (const float*)d_in[14], (const float*)d_in[15],
        (float*)d_out);
}

// Round 5
// 492.669 us; speedup vs baseline: 1.0405x; 1.0405x over previous
//
#include <hip/hip_runtime.h>

// QSScan: quantized selective scan (Mamba-style), int8-in-int32 + scalar scales.
// Chunked parallel linear recurrence:
//   phase1: per (scan, chunk) local scan from zero -> X_end[16], P=exp2(A2*sum_delta)[16]
//   combine: per (scan, n) sequential fold over 32 chunks -> true init state per chunk
//   phase2: per (scan, chunk) rerun with true init, emit y = (x.C)*C_s + D*u, gated by silu(z)
// All states live in registers (16 fp32/thread); no shuffles, no syncthreads in hot loops.

#define LOG2E 1.44269504088896340736f
#define LN2F  0.69314718055994530942f

constexpr int BATCH = 2;
constexpr int DIM   = 4096;
constexpr int LSEQ  = 2048;
constexpr int NST   = 16;
constexpr int SCANS = BATCH * DIM;   // 8192
constexpr int K     = 32;            // chunks per scan
constexpr int LC    = LSEQ / K;      // 64 timesteps per chunk
constexpr int SG    = 256;           // scans per block (one chunk per block)

__device__ __forceinline__ float softplus_f(float x) {
    // x in [-3.1, 3.1] here: naive log(1+exp(x)) is safe
    float e = __builtin_amdgcn_exp2f(x * LOG2E);
    return __builtin_amdgcn_logf(1.f + e) * LN2F;
}

#define LOAD_A2()                                                              \
    float A2[NST];                                                             \
    {                                                                          \
        const int4* ap = (const int4*)(A_log + (size_t)d * NST);               \
        int4 a0 = ap[0], a1 = ap[1], a2 = ap[2], a3 = ap[3];                   \
        const int ai[NST] = {a0.x,a0.y,a0.z,a0.w, a1.x,a1.y,a1.z,a1.w,         \
                             a2.x,a2.y,a2.z,a2.w, a3.x,a3.y,a3.z,a3.w};        \
        _Pragma("unroll")                                                      \
        for (int n = 0; n < NST; ++n)                                          \
            A2[n] = -__builtin_amdgcn_exp2f((float)ai[n] * (A_s * LOG2E)) * LOG2E; \
    }

// ---------------- Phase 1: per-chunk summaries ----------------
__global__ __launch_bounds__(256, 4) void qs_phase1(
    const int* __restrict__ u,  const int* __restrict__ dt,
    const int* __restrict__ Bm, const int* __restrict__ A_log,
    const int* __restrict__ dt_bias,
    const float* __restrict__ u_sp, const float* __restrict__ dt_sp,
    const float* __restrict__ A_sp, const float* __restrict__ B_sp,
    const float* __restrict__ dtb_sp,
    float* __restrict__ Pbuf, float* __restrict__ Xbuf)
{
    const int tid  = threadIdx.x;
    const int c    = blockIdx.x & (K - 1);
    const int sg   = blockIdx.x >> 5;            // log2(K) = 5
    const int scan = sg * SG + tid;
    const int d    = scan & (DIM - 1);
    const int bb   = (sg * SG) >> 12;            // batch, uniform per block
    const int t0   = c * LC;

    const float u_s = *u_sp, dt_s = *dt_sp, A_s = *A_sp, B_s = *B_sp, dtb_s = *dtb_sp;

    // stage B tile [LC][NST] as float (uniform-address broadcast reads later)
    __shared__ float tB[LC][NST];
    {
        const int n0 = tid >> 4, tt0 = (tid & 15) * 4;
        const int4 v = *(const int4*)(Bm + ((size_t)bb * NST + n0) * LSEQ + t0 + tt0);
        tB[tt0 + 0][n0] = (float)v.x;
        tB[tt0 + 1][n0] = (float)v.y;
        tB[tt0 + 2][n0] = (float)v.z;
        tB[tt0 + 3][n0] = (float)v.w;
    }
    __syncthreads();

    LOAD_A2();
    const float dtb = (float)dt_bias[d] * dtb_s;

    const int* up = u  + (size_t)scan * LSEQ + t0;
    const int* dp = dt + (size_t)scan * LSEQ + t0;

    float x[NST];
#pragma unroll
    for (int n = 0; n < NST; ++n) x[n] = 0.f;
    float S = 0.f;

    for (int tt = 0; tt < LC; tt += 4) {
        const int4 uv = *(const int4*)(up + tt);
        const int4 dv = *(const int4*)(dp + tt);
        const int ua[4] = {uv.x, uv.y, uv.z, uv.w};
        const int da[4] = {dv.x, dv.y, dv.z, dv.w};
#pragma unroll
        for (int k = 0; k < 4; ++k) {
            const float delta = softplus_f((float)da[k] * dt_s + dtb);
            const float wB    = delta * ((float)ua[k] * u_s) * B_s;
            S += delta;
            const float4* bt = (const float4*)&tB[tt + k][0];
            const float4 B0 = bt[0], B1 = bt[1], B2 = bt[2], B3 = bt[3];
            const float Bt[NST] = {B0.x,B0.y,B0.z,B0.w, B1.x,B1.y,B1.z,B1.w,
                                   B2.x,B2.y,B2.z,B2.w, B3.x,B3.y,B3.z,B3.w};
#pragma unroll
            for (int n = 0; n < NST; ++n)
                x[n] = __builtin_fmaf(__builtin_amdgcn_exp2f(A2[n] * delta), x[n], wB * Bt[n]);
        }
    }

    const size_t off = ((size_t)c * SCANS + scan) * NST;
    float4* Xo = (float4*)(Xbuf + off);
    float4* Po = (float4*)(Pbuf + off);
#pragma unroll
    for (int q = 0; q < 4; ++q) {
        Xo[q] = make_float4(x[4*q], x[4*q+1], x[4*q+2], x[4*q+3]);
        Po[q] = make_float4(__builtin_amdgcn_exp2f(A2[4*q+0] * S),
                            __builtin_amdgcn_exp2f(A2[4*q+1] * S),
                            __builtin_amdgcn_exp2f(A2[4*q+2] * S),
                            __builtin_amdgcn_exp2f(A2[4*q+3] * S));
    }
}

// ---------------- Combine: fold summaries, write init states in-place ----------------
__global__ __launch_bounds__(256) void qs_combine(
    const float* __restrict__ Pbuf, float* __restrict__ Xbuf)
{
    const int idx = blockIdx.x * 256 + threadIdx.x;   // (scan, n) flat: SCANS*NST
    float Pv[K], Xv[K];
#pragma unroll
    for (int c = 0; c < K; ++c) {
        const size_t off = (size_t)c * (SCANS * NST) + idx;
        Pv[c] = Pbuf[off];
        Xv[c] = Xbuf[off];
    }
    float x = 0.f;
#pragma unroll
    for (int c = 0; c < K; ++c) {
        const size_t off = (size_t)c * (SCANS * NST) + idx;
        Xbuf[off] = x;                                 // init state for chunk c
        x = __builtin_fmaf(Pv[c], x, Xv[c]);
    }
}

// ---------------- Phase 2: full scan per chunk with true init, emit output ----------------
__global__ __launch_bounds__(256, 4) void qs_phase2(
    const int* __restrict__ u,  const int* __restrict__ dt,
    const int* __restrict__ Bm, const int* __restrict__ Cm,
    const int* __restrict__ z,  const int* __restrict__ A_log,
    const int* __restrict__ Dv, const int* __restrict__ dt_bias,
    const float* __restrict__ u_sp,  const float* __restrict__ dt_sp,
    const float* __restrict__ A_sp,  const float* __restrict__ B_sp,
    const float* __restrict__ C_sp,  const float* __restrict__ z_sp,
    const float* __restrict__ D_sp,  const float* __restrict__ dtb_sp,
    const float* __restrict__ XI,    // init states (Xbuf after combine)
    float* __restrict__ out)
{
    const int tid  = threadIdx.x;
    const int c    = blockIdx.x & (K - 1);
    const int sg   = blockIdx.x >> 5;
    const int scan = sg * SG + tid;
    const int d    = scan & (DIM - 1);
    const int bb   = (sg * SG) >> 12;
    const int t0   = c * LC;

    const float u_s = *u_sp, dt_s = *dt_sp, A_s = *A_sp, B_s = *B_sp;
    const float C_s = *C_sp, z_s  = *z_sp,  D_s = *D_sp, dtb_s = *dtb_sp;

    __shared__ float tB[LC][NST];
    __shared__ float tC[LC][NST];
    {
        const int n0 = tid >> 4, tt0 = (tid & 15) * 4;
        const size_t row = ((size_t)bb * NST + n0) * LSEQ + t0 + tt0;
        const int4 vb = *(const int4*)(Bm + row);
        const int4 vc = *(const int4*)(Cm + row);
        tB[tt0 + 0][n0] = (float)vb.x; tB[tt0 + 1][n0] = (float)vb.y;
        tB[tt0 + 2][n0] = (float)vb.z; tB[tt0 + 3][n0] = (float)vb.w;
        tC[tt0 + 0][n0] = (float)vc.x; tC[tt0 + 1][n0] = (float)vc.y;
        tC[tt0 + 2][n0] = (float)vc.z; tC[tt0 + 3][n0] = (float)vc.w;
    }
    __syncthreads();

    LOAD_A2();
    const float dtb = (float)dt_bias[d] * dtb_s;
    const float Dd  = (float)Dv[d] * D_s;

    // true init state for this chunk
    float x[NST];
    {
        const float4* xi = (const float4*)(XI + ((size_t)c * SCANS + scan) * NST);
        const float4 x0 = xi[0], x1 = xi[1], x2 = xi[2], x3 = xi[3];
        const float xin[NST] = {x0.x,x0.y,x0.z,x0.w, x1.x,x1.y,x1.z,x1.w,
                                x2.x,x2.y,x2.z,x2.w, x3.x,x3.y,x3.z,x3.w};
#pragma unroll
        for (int n = 0; n < NST; ++n) x[n] = xin[n];
    }

    const int* up = u  + (size_t)scan * LSEQ + t0;
    const int* dp = dt + (size_t)scan * LSEQ + t0;
    const int* zp = z  + (size_t)scan * LSEQ + t0;
    float*     op = out + (size_t)scan * LSEQ + t0;

    for (int tt = 0; tt < LC; tt += 4) {
        const int4 uv = *(const int4*)(up + tt);
        const int4 dv = *(const int4*)(dp + tt);
        const int4 zv = *(const int4*)(zp + tt);
        const int ua[4] = {uv.x, uv.y, uv.z, uv.w};
        const int da[4] = {dv.x, dv.y, dv.z, dv.w};
        const int za[4] = {zv.x, zv.y, zv.z, zv.w};
        float ya[4];
#pragma unroll
        for (int k = 0; k < 4; ++k) {
            const float uf    = (float)ua[k] * u_s;
            const float delta = softplus_f((float)da[k] * dt_s + dtb);
            const float wB    = delta * uf * B_s;
            const float zf    = (float)za[k] * z_s;
            const float gate  = zf * __builtin_amdgcn_rcpf(
                                    1.f + __builtin_amdgcn_exp2f(-zf * LOG2E));
            const float4* bt = (const float4*)&tB[tt + k][0];
            const float4* ct = (const float4*)&tC[tt + k][0];
            const float4 B0 = bt[0], B1 = bt[1], B2 = bt[2], B3 = bt[3];
            const float4 C0 = ct[0], C1 = ct[1], C2 = ct[2], C3 = ct[3];
            const float Bt[NST] = {B0.x,B0.y,B0.z,B0.w, B1.x,B1.y,B1.z,B1.w,
                                   B2.x,B2.y,B2.z,B2.w, B3.x,B3.y,B3.z,B3.w};
            const float Ct[NST] = {C0.x,C0.y,C0.z,C0.w, C1.x,C1.y,C1.z,C1.w,
                                   C2.x,C2.y,C2.z,C2.w, C3.x,C3.y,C3.z,C3.w};
            float y = 0.f;
#pragma unroll
            for (int n = 0; n < NST; ++n) {
                x[n] = __builtin_fmaf(__builtin_amdgcn_exp2f(A2[n] * delta), x[n], wB * Bt[n]);
                y    = __builtin_fmaf(x[n], Ct[n], y);
            }
            ya[k] = __builtin_fmaf(y, C_s, Dd * uf) * gate;
        }
        *(float4*)(op + tt) = make_float4(ya[0], ya[1], ya[2], ya[3]);
    }
}

extern "C" void kernel_launch(void* const* d_in, const int* in_sizes, int n_in,
                              void* d_out, int out_size, void* d_ws, size_t ws_size,
                              hipStream_t stream) {
    const int* u   = (const int*)d_in[0];
    const int* dt  = (const int*)d_in[1];
    const int* Bm  = (const int*)d_in[2];
    const int* Cm  = (const int*)d_in[3];
    const int* z   = (const int*)d_in[4];
    const int* Al  = (const int*)d_in[5];
    const int* Dv  = (const int*)d_in[6];
    const int* dtb = (const int*)d_in[7];
    const float* u_sp = (const float*)d_in[8],  * dt_sp = (const float*)d_in[9];
    const float* A_sp = (const float*)d_in[10], * B_sp  = (const float*)d_in[11];
    const float* C_sp = (const float*)d_in[12], * z_sp  = (const float*)d_in[13];
    const float* D_sp = (const float*)d_in[14], * dtb_sp= (const float*)d_in[15];

    float* Pbuf = (float*)d_ws;                              // K*SCANS*NST f32 = 16 MiB
    float* Xbuf = Pbuf + (size_t)K * SCANS * NST;            // 16 MiB more

    dim3 blk(256);
    qs_phase1<<<dim3(32 * K), blk, 0, stream>>>(u, dt, Bm, Al, dtb,
        u_sp, dt_sp, A_sp, B_sp, dtb_sp, Pbuf, Xbuf);
    qs_combine<<<dim3(SCANS * NST / 256), blk, 0, stream>>>(Pbuf, Xbuf);
    qs_phase2<<<dim3(32 * K), blk, 0, stream>>>(u, dt, Bm, Cm, z, Al, Dv, dtb,
        u_sp, dt_sp, A_sp, B_sp, C_sp, z_sp, D_sp, dtb_sp, Xbuf, (float*)d_out);
}